// Round 1
// baseline (56.651 us; speedup 1.0000x reference)
//
#include <hip/hip_runtime.h>

// LDDMM Hamiltonian evolution: closed-form gradients of
// H = sum_ij exp(-||x_i-x_j||^2/sigma^2) <m_i, m_j>,  sigma = 0.1
// out0 = -dH/dpos = (4/sigma^2) * sum_j K_ij (m_i.m_j) (x_i - x_j)
// out1 =  dH/dmom = 2 * sum_j K_ij m_j
//
// N=8192, D=3, B=1. Compute-bound (67M pairs x ~18 VALU + exp).
// 256 blocks x 512 threads; 32 i-points/block, 16 sub-threads per i.
// j staged in LDS as float4 (positions pre-scaled by 10 so that
// d2_scaled = 100*d2 and K = expf(-d2_scaled); final pos-grad scale 400/10=40).

constexpr int NSUB  = 16;           // threads cooperating on one i
constexpr int IPB   = 32;           // i points per block
constexpr int BLOCK = NSUB * IPB;   // 512 threads
constexpr int TJ    = 256;          // j tile size staged in LDS

__global__ __launch_bounds__(BLOCK)
void lddmm_hamilton(const float* __restrict__ mom,
                    const float* __restrict__ pos,
                    float* __restrict__ out, int N)
{
    __shared__ float4 sp[TJ];   // scaled positions (x,y,z,0)
    __shared__ float4 sm[TJ];   // momenta (x,y,z,0)

    const int tid = threadIdx.x;
    const int sub = tid & (NSUB - 1);
    const int il  = tid >> 4;                  // log2(NSUB) = 4
    const int i   = blockIdx.x * IPB + il;
    const int ic  = (i < N) ? i : 0;

    const float xi  = 10.0f * pos[ic * 3 + 0];
    const float yi  = 10.0f * pos[ic * 3 + 1];
    const float zi  = 10.0f * pos[ic * 3 + 2];
    const float mxi = mom[ic * 3 + 0];
    const float myi = mom[ic * 3 + 1];
    const float mzi = mom[ic * 3 + 2];

    float fx = 0.f, fy = 0.f, fz = 0.f;   // sum e*(m_i.m_j)*(xi-xj)  (scaled coords)
    float gx = 0.f, gy = 0.f, gz = 0.f;   // sum e*m_j

    for (int jt = 0; jt < N; jt += TJ) {
        __syncthreads();   // previous tile fully consumed before overwrite
        if (tid < TJ) {
            const int jg = jt + tid;
            float4 v = make_float4(0.f, 0.f, 0.f, 0.f);
            if (jg < N) {
                v.x = 10.0f * pos[jg * 3 + 0];
                v.y = 10.0f * pos[jg * 3 + 1];
                v.z = 10.0f * pos[jg * 3 + 2];
            }
            sp[tid] = v;
        } else {
            const int t  = tid - TJ;
            const int jg = jt + t;
            float4 v = make_float4(0.f, 0.f, 0.f, 0.f);  // mom=0 pad => contributes 0
            if (jg < N) {
                v.x = mom[jg * 3 + 0];
                v.y = mom[jg * 3 + 1];
                v.z = mom[jg * 3 + 2];
            }
            sm[t] = v;
        }
        __syncthreads();

        #pragma unroll
        for (int k = 0; k < TJ / NSUB; ++k) {
            const int j = k * NSUB + sub;
            const float4 p = sp[j];
            const float4 m = sm[j];
            const float dx = xi - p.x;
            const float dy = yi - p.y;
            const float dz = zi - p.z;
            const float d2 = dx * dx + dy * dy + dz * dz;
            const float e  = __expf(-d2);              // = exp(-100*||xi-xj||^2)
            const float md = mxi * m.x + myi * m.y + mzi * m.z;
            const float w  = e * md;
            fx += w * dx;  fy += w * dy;  fz += w * dz;
            gx += e * m.x; gy += e * m.y; gz += e * m.z;
        }
    }

    // reduce the 16 sub-lanes of each i (xor masks stay inside 16-lane groups)
    #pragma unroll
    for (int msk = 1; msk < NSUB; msk <<= 1) {
        fx += __shfl_xor(fx, msk);
        fy += __shfl_xor(fy, msk);
        fz += __shfl_xor(fz, msk);
        gx += __shfl_xor(gx, msk);
        gy += __shfl_xor(gy, msk);
        gz += __shfl_xor(gz, msk);
    }

    if (sub == 0 && i < N) {
        // out0 = -dH/dpos: scale = (4/sigma^2) / 10 = 400/10 = 40 (coords were x10)
        out[i * 3 + 0] = 40.0f * fx;
        out[i * 3 + 1] = 40.0f * fy;
        out[i * 3 + 2] = 40.0f * fz;
        // out1 = dH/dmom = 2 * sum K m_j
        float* o2 = out + (size_t)N * 3;
        o2[i * 3 + 0] = 2.0f * gx;
        o2[i * 3 + 1] = 2.0f * gy;
        o2[i * 3 + 2] = 2.0f * gz;
    }
}

extern "C" void kernel_launch(void* const* d_in, const int* in_sizes, int n_in,
                              void* d_out, int out_size, void* d_ws, size_t ws_size,
                              hipStream_t stream) {
    const float* mom = (const float*)d_in[0];
    const float* pos = (const float*)d_in[1];
    float* out = (float*)d_out;
    const int N = in_sizes[0] / 3;   // B=1, D=3
    const int nblocks = (N + IPB - 1) / IPB;
    lddmm_hamilton<<<dim3(nblocks), dim3(BLOCK), 0, stream>>>(mom, pos, out, N);
}

// Round 2
// 47.855 us; speedup vs baseline: 1.1838x; 1.1838x over previous
//
#include <hip/hip_runtime.h>

// LDDMM Hamiltonian evolution, closed-form gradients of
// H = sum_ij exp(-||x_i-x_j||^2/sigma^2) <m_i,m_j>, sigma=0.1:
//   out0 = -dH/dpos = (4/sigma^2) * sum_j K_ij (m_i.m_j)(x_i-x_j)
//   out1 =  dH/dmom = 2 * sum_j K_ij m_j
//
// R1 redesign: register-tile MI=4 i's per thread (cuts LDS bytes/pair 32->8,
// removing the 2x LDS-BW oversubscription seen in R0's VALUBusy=48%), and
// split the j-range G=4 ways across grid.y for occupancy (R0 was 1 block/CU).
// Partials go to d_ws; a small second kernel reduces deterministically.
// Coordinates pre-scaled by 10*sqrt(log2 e) so K = exp2(-d2) directly.

constexpr int MI    = 4;          // i-points per thread (register tile)
constexpr int WPB   = 4;          // waves per block
constexpr int BLOCK = WPB * 64;   // 256 threads
constexpr int IPB   = WPB * MI;   // 16 i-points per block
constexpr int G     = 4;          // j-range split factor (grid.y)
constexpr int TJ    = 512;        // j-tile staged in LDS (16 KiB)

constexpr double S_D        = 12.011224087864498;      // 10*sqrt(log2(e))
constexpr float  SCALE_POS  = (float)S_D;
constexpr float  SCALE_F    = (float)(400.0 / S_D);    // (4/sigma^2)/S_D

#if __has_builtin(__builtin_amdgcn_exp2f)
#define EXP2F(x) __builtin_amdgcn_exp2f(x)
#else
#define EXP2F(x) exp2f(x)
#endif

template <bool ATOMIC>
__global__ __launch_bounds__(BLOCK)
void lddmm_partial(const float* __restrict__ mom, const float* __restrict__ pos,
                   float* __restrict__ outw, int N)
{
    __shared__ float4 sp[TJ];   // scaled positions (x,y,z,0)
    __shared__ float4 sm[TJ];   // momenta (x,y,z,0)

    const int tid  = threadIdx.x;
    const int lane = tid & 63;
    const int wid  = tid >> 6;
    const int i0   = blockIdx.x * IPB + wid * MI;   // this wave's 4 i's
    const int jStart = blockIdx.y * (N / G);
    const int jEnd   = jStart + N / G;

    float xi[MI], yi[MI], zi[MI], mxi[MI], myi[MI], mzi[MI];
    #pragma unroll
    for (int u = 0; u < MI; ++u) {
        int i = i0 + u; if (i >= N) i = N - 1;      // N%IPB==0 in practice
        xi[u]  = SCALE_POS * pos[i * 3 + 0];
        yi[u]  = SCALE_POS * pos[i * 3 + 1];
        zi[u]  = SCALE_POS * pos[i * 3 + 2];
        mxi[u] = mom[i * 3 + 0];
        myi[u] = mom[i * 3 + 1];
        mzi[u] = mom[i * 3 + 2];
    }

    float fx[MI] = {}, fy[MI] = {}, fz[MI] = {};
    float gx[MI] = {}, gyv[MI] = {}, gz[MI] = {};

    for (int jt = jStart; jt < jEnd; jt += TJ) {
        __syncthreads();
        #pragma unroll
        for (int r = tid; r < TJ; r += BLOCK) {     // 2 points per thread
            const int jg = jt + r;
            float4 p = make_float4(0.f, 0.f, 0.f, 0.f);
            float4 m = make_float4(0.f, 0.f, 0.f, 0.f);  // mom=0 pad -> 0 contrib
            if (jg < N) {
                p.x = SCALE_POS * pos[jg * 3 + 0];
                p.y = SCALE_POS * pos[jg * 3 + 1];
                p.z = SCALE_POS * pos[jg * 3 + 2];
                m.x = mom[jg * 3 + 0];
                m.y = mom[jg * 3 + 1];
                m.z = mom[jg * 3 + 2];
            }
            sp[r] = p;
            sm[r] = m;
        }
        __syncthreads();

        for (int t = 0; t < TJ; t += 64) {
            const float4 p = sp[t + lane];
            const float4 m = sm[t + lane];
            #pragma unroll
            for (int u = 0; u < MI; ++u) {
                const float dx = xi[u] - p.x;
                const float dy = yi[u] - p.y;
                const float dz = zi[u] - p.z;
                const float d2 = dx * dx + dy * dy + dz * dz;
                const float e  = EXP2F(-d2);        // = exp(-100*||.||^2) via prescale
                const float md = fmaf(mxi[u], m.x, fmaf(myi[u], m.y, mzi[u] * m.z));
                const float w  = e * md;
                fx[u]  = fmaf(w, dx, fx[u]);
                fy[u]  = fmaf(w, dy, fy[u]);
                fz[u]  = fmaf(w, dz, fz[u]);
                gx[u]  = fmaf(e, m.x, gx[u]);
                gyv[u] = fmaf(e, m.y, gyv[u]);
                gz[u]  = fmaf(e, m.z, gz[u]);
            }
        }
    }

    // full-wave butterfly reduction of the 24 accumulators
    #pragma unroll
    for (int msk = 1; msk < 64; msk <<= 1) {
        #pragma unroll
        for (int u = 0; u < MI; ++u) {
            fx[u]  += __shfl_xor(fx[u],  msk);
            fy[u]  += __shfl_xor(fy[u],  msk);
            fz[u]  += __shfl_xor(fz[u],  msk);
            gx[u]  += __shfl_xor(gx[u],  msk);
            gyv[u] += __shfl_xor(gyv[u], msk);
            gz[u]  += __shfl_xor(gz[u],  msk);
        }
    }

    if (lane == 0) {
        #pragma unroll
        for (int u = 0; u < MI; ++u) {
            const int i = i0 + u;
            if (i < N) {
                if (ATOMIC) {
                    atomicAdd(&outw[i * 3 + 0], SCALE_F * fx[u]);
                    atomicAdd(&outw[i * 3 + 1], SCALE_F * fy[u]);
                    atomicAdd(&outw[i * 3 + 2], SCALE_F * fz[u]);
                    float* o2 = outw + (size_t)N * 3;
                    atomicAdd(&o2[i * 3 + 0], 2.0f * gx[u]);
                    atomicAdd(&o2[i * 3 + 1], 2.0f * gyv[u]);
                    atomicAdd(&o2[i * 3 + 2], 2.0f * gz[u]);
                } else {
                    float* p = outw + ((size_t)blockIdx.y * N + i) * 6;
                    p[0] = fx[u]; p[1] = fy[u]; p[2] = fz[u];
                    p[3] = gx[u]; p[4] = gyv[u]; p[5] = gz[u];
                }
            }
        }
    }
}

__global__ void lddmm_reduce(const float* __restrict__ ws, float* __restrict__ out, int N)
{
    const int i = blockIdx.x * blockDim.x + threadIdx.x;
    if (i >= N) return;
    float s0 = 0.f, s1 = 0.f, s2 = 0.f, s3 = 0.f, s4 = 0.f, s5 = 0.f;
    #pragma unroll
    for (int g = 0; g < G; ++g) {
        const float* p = ws + ((size_t)g * N + i) * 6;
        s0 += p[0]; s1 += p[1]; s2 += p[2];
        s3 += p[3]; s4 += p[4]; s5 += p[5];
    }
    out[i * 3 + 0] = SCALE_F * s0;
    out[i * 3 + 1] = SCALE_F * s1;
    out[i * 3 + 2] = SCALE_F * s2;
    float* o2 = out + (size_t)N * 3;
    o2[i * 3 + 0] = 2.0f * s3;
    o2[i * 3 + 1] = 2.0f * s4;
    o2[i * 3 + 2] = 2.0f * s5;
}

extern "C" void kernel_launch(void* const* d_in, const int* in_sizes, int n_in,
                              void* d_out, int out_size, void* d_ws, size_t ws_size,
                              hipStream_t stream) {
    const float* mom = (const float*)d_in[0];
    const float* pos = (const float*)d_in[1];
    float* out = (float*)d_out;
    const int N = in_sizes[0] / 3;   // B=1, D=3

    const dim3 grid((N + IPB - 1) / IPB, G);
    const size_t need = (size_t)G * N * 6 * sizeof(float);

    if (d_ws != nullptr && ws_size >= need) {
        float* ws = (float*)d_ws;
        lddmm_partial<false><<<grid, dim3(BLOCK), 0, stream>>>(mom, pos, ws, N);
        lddmm_reduce<<<(N + 255) / 256, 256, 0, stream>>>(ws, out, N);
    } else {
        // fallback: accumulate directly with atomics (out zeroed first)
        hipMemsetAsync(d_out, 0, (size_t)out_size * sizeof(float), stream);
        lddmm_partial<true><<<grid, dim3(BLOCK), 0, stream>>>(mom, pos, out, N);
    }
}